// Round 2
// baseline (373.127 us; speedup 1.0000x reference)
//
#include <hip/hip_runtime.h>

// Loss kernel, two-phase:
//   1) pure float4 memcpy y -> out (340 MB traffic, branch-free, copy roofline ~54us)
//   2) head overwrite: out[row, 0:5] = {bx, by, bw, bh, 0} (2.5M scalar stores, ~5-10us)
// N=500000, D=85, f32.

#define D_COLS 85
#define AC_CONST 1e-16f

__global__ __launch_bounds__(256) void copy_kernel(const float4* __restrict__ y4,
                                                   float4* __restrict__ o4,
                                                   int n4) {
    const int stride = gridDim.x * blockDim.x;
    for (int i = blockIdx.x * blockDim.x + threadIdx.x; i < n4; i += stride) {
        o4[i] = y4[i];
    }
}

__global__ __launch_bounds__(256) void head_kernel(const float* __restrict__ x,
                                                   const float* __restrict__ y,
                                                   float* __restrict__ out,
                                                   int nhead /* = N*5 */) {
    // Head scalars (broadcast loads, cached; trivial ALU, once per thread).
    const float px = x[0];
    const float py = x[1];
    const float tx = y[0];
    const float ty = y[1];
    const float bx = 1.0f / (1.0f + expf(-px)) + tx;   // sigmoid(px) + tx
    const float by = 1.0f / (1.0f + expf(-py)) + ty;   // sigmoid(py) + ty
    const float bw = AC_CONST * expf(px);              // replicates source's use of px
    const float bh = AC_CONST * expf(py);              // replicates source's use of py

    const int h = blockIdx.x * blockDim.x + threadIdx.x;
    if (h >= nhead) return;
    const int row = h / 5;          // constant divisor -> magic multiply
    const int c = h - row * 5;      // column in [0,5)
    const float v = (c == 0) ? bx
                  : (c == 1) ? by
                  : (c == 2) ? bw
                  : (c == 3) ? bh
                  : 0.0f;           // c == 4: objectness column zeroed
    out[row * D_COLS + c] = v;
}

extern "C" void kernel_launch(void* const* d_in, const int* in_sizes, int n_in,
                              void* d_out, int out_size, void* d_ws, size_t ws_size,
                              hipStream_t stream) {
    const float* x = (const float*)d_in[0];
    const float* y = (const float*)d_in[1];
    float* out = (float*)d_out;

    const int total = out_size;          // 500000 * 85 = 42,500,000 (divisible by 4)
    const int n4 = total / 4;            // 10,625,000 float4s, no tail

    // Phase 1: branch-free flat copy.
    {
        const int block = 256;
        int grid = (n4 + block - 1) / block;
        const int max_grid = 256 * 8;    // 2048 blocks, grid-stride the rest
        if (grid > max_grid) grid = max_grid;
        copy_kernel<<<grid, block, 0, stream>>>(
            reinterpret_cast<const float4*>(y), reinterpret_cast<float4*>(out), n4);
    }

    // Phase 2: overwrite the 5-column head (serialized after copy on the stream).
    {
        const int nrows = total / D_COLS;   // 500,000
        const int nhead = nrows * 5;        // 2,500,000
        const int block = 256;
        const int grid = (nhead + block - 1) / block;
        head_kernel<<<grid, block, 0, stream>>>(x, y, out, nhead);
    }
}

// Round 6
// 339.276 us; speedup vs baseline: 1.0998x; 1.0998x over previous
//
#include <hip/hip_runtime.h>

// Fused loss kernel: out[v,0:4]={bx,by,bw,bh}, out[v,4]=0, out[v,5:]=y[v,5:]
// N=500000, D=85, f32. Memory-bound: 170MB read + 170MB write -> ~52-55us kernel
// at ~6.5 TB/s achieved copy BW. ALU (col tracking + head select) is ~8% of the
// memory time -> hidden. Single kernel (round-2 split regressed +27us: head RMW
// partial-line writes + extra launch).
// Nontemporal builtins need a NATIVE clang vector type (ext_vector_type), not
// HIP_vector_type<float,4> (round-5 compile error).

#define D_COLS 85
#define AC_CONST 1e-16f

typedef float vf4 __attribute__((ext_vector_type(4)));

__global__ __launch_bounds__(256) void loss_kernel(const float* __restrict__ x,
                                                   const float* __restrict__ y,
                                                   float* __restrict__ out,
                                                   int n4 /* number of float4 elements */) {
    // Head scalars: computed once per thread (broadcast loads, cached).
    const float px = x[0];
    const float py = x[1];
    const float tx = y[0];
    const float ty = y[1];
    const float bx = 1.0f / (1.0f + expf(-px)) + tx;   // sigmoid(px) + tx
    const float by = 1.0f / (1.0f + expf(-py)) + ty;   // sigmoid(py) + ty
    const float bw = AC_CONST * expf(px);              // replicates source's use of px
    const float bh = AC_CONST * expf(py);              // replicates source's use of py

    const vf4* __restrict__ y4 = reinterpret_cast<const vf4*>(y);
    vf4* __restrict__ o4 = reinterpret_cast<vf4*>(out);

    const int stride = gridDim.x * blockDim.x;   // threads in grid
    int i = blockIdx.x * blockDim.x + threadIdx.x;
    if (i >= n4) return;

    // Column of element 4*i, tracked incrementally: one div at entry,
    // then c0 += (4*stride) mod 85 with a conditional subtract per iteration.
    int c0 = (i * 4) % D_COLS;                   // magic-mul div, once
    const int inc = (int)(((long long)stride * 4) % D_COLS);

    for (; i < n4; i += stride) {
        vf4 v = __builtin_nontemporal_load(&y4[i]);

        // Head patch: this float4 (cols c0..c0+3, mod 85) overlaps cols 0..4
        // iff c0 < 5 or c0 > 81. ~9% of lanes per wave; fast path is trivial.
        if (c0 < 5 || c0 > D_COLS - 4) {
            #pragma unroll
            for (int j = 0; j < 4; ++j) {
                int c = c0 + j;
                if (c >= D_COLS) c -= D_COLS;
                if (c < 5) {
                    v[j] = (c == 0) ? bx
                         : (c == 1) ? by
                         : (c == 2) ? bw
                         : (c == 3) ? bh
                         : 0.0f;              // c == 4: objectness column zeroed
                }
            }
        }
        __builtin_nontemporal_store(v, &o4[i]);

        c0 += inc;
        if (c0 >= D_COLS) c0 -= D_COLS;
    }
}

extern "C" void kernel_launch(void* const* d_in, const int* in_sizes, int n_in,
                              void* d_out, int out_size, void* d_ws, size_t ws_size,
                              hipStream_t stream) {
    const float* x = (const float*)d_in[0];
    const float* y = (const float*)d_in[1];
    float* out = (float*)d_out;

    const int total = out_size;          // 500000 * 85 = 42,500,000 (divisible by 4)
    const int n4 = total / 4;            // 10,625,000 float4s, no tail

    const int block = 256;
    int grid = (n4 + block - 1) / block;
    const int max_grid = 256 * 8;        // 2048 blocks; grid-stride the rest (~21 iters)
    if (grid > max_grid) grid = max_grid;

    loss_kernel<<<grid, block, 0, stream>>>(x, y, out, n4);
}